// Round 3
// baseline (662.181 us; speedup 1.0000x reference)
//
#include <hip/hip_runtime.h>
#include <stdint.h>
#include <stddef.h>

#define T_LEN   2000
#define BATCH   32
#define ROWS    64000      /* B*T */
#define KDIM    1024
#define ADIM    512
#define CCH     32
#define KW      101        /* 2*50+1 */
#define PADA    40         /* A-tile LDS row stride in f16 (pad 32->40) */

typedef _Float16 half8_t  __attribute__((ext_vector_type(8)));
typedef float    float4_t __attribute__((ext_vector_type(4)));

__device__ __forceinline__ half8_t pack8(float4_t a, float4_t b) {
    half8_t r;
    r[0] = (_Float16)a.x; r[1] = (_Float16)a.y;
    r[2] = (_Float16)a.z; r[3] = (_Float16)a.w;
    r[4] = (_Float16)b.x; r[5] = (_Float16)b.y;
    r[6] = (_Float16)b.z; r[7] = (_Float16)b.w;
    return r;
}

__device__ __forceinline__ float tanh_fast(float x) {
    float ax = __builtin_fabsf(x);
    ax = fminf(ax, 15.f);
    float e = __expf(2.f * ax);
    float t = 1.f - 2.f * __builtin_amdgcn_rcpf(e + 1.f);
    return (x < 0.f) ? -t : t;
}

/* async global->LDS, 16B per lane; LDS dest = wave-uniform base + lane*16 */
__device__ __forceinline__ void glds16(const void* g, void* l) {
    __builtin_amdgcn_global_load_lds((const __attribute__((address_space(1))) uint32_t*)g,
                                     (__attribute__((address_space(3))) uint32_t*)l,
                                     16, 0, 0);
}

/* ---- ws layout (bytes) ---- */
#define OFF_WENCT 0                 /* 512*1024 f16 = 1048576 */
#define OFF_WATTT 1048576           /* 512*32  f16 = 32768   */
#define OFF_CONVA 1081344           /* 64000*32 f16 = 4096000 */
#define OFF_DTERM 5177344           /* 32*512 f32 = 65536    */
#define OFF_EPART 5242880           /* 64000 f32 = 256000    */
#define OFF_CPART 5498880           /* 16*32*1024 f32 = 2097152 -> end 7596032 */

/* ---- fused prep: blocks [0,512) We transpose, [512,640) dterm,
 *      [640,1152) conv, [1152] Wat transpose. 256 threads. ---- */
__global__ __launch_bounds__(256) void k_prep(const float* __restrict__ We,
                                              const float* __restrict__ Wa,
                                              const float* __restrict__ dec_h,
                                              const float* __restrict__ W_dec,
                                              const float* __restrict__ be,
                                              const float* __restrict__ bd,
                                              const float* __restrict__ ba,
                                              const float* __restrict__ att_prev,
                                              const float* __restrict__ conv_w,
                                              _Float16* __restrict__ Wet,
                                              _Float16* __restrict__ Wat,
                                              float* __restrict__ dterm,
                                              _Float16* __restrict__ convA) {
    __shared__ float smem[3460];
    const int blk = blockIdx.x, tid = threadIdx.x;

    if (blk < 512) {
        /* W_enc [k=1024][n=512] -> Wet f16 [n][k], LDS tile transpose */
        float (*tile)[33] = (float(*)[33])smem;
        const int k0 = (blk >> 4) * 32, n0 = (blk & 15) * 32;
        const int tx = tid & 31, ty = tid >> 5;
#pragma unroll
        for (int i = 0; i < 4; ++i)
            tile[ty + i * 8][tx] = We[(size_t)(k0 + ty + i * 8) * ADIM + n0 + tx];
        __syncthreads();
#pragma unroll
        for (int i = 0; i < 4; ++i)
            Wet[(size_t)(n0 + ty + i * 8) * KDIM + k0 + tx] = (_Float16)tile[tx][ty + i * 8];
    } else if (blk < 640) {
        /* dterm[b][a] = dec_h[b]@W_dec + be + bd + ba */
        float* dh = smem;            /* 1024 */
        float* part = smem + 1024;   /* 256  */
        const int idx = blk - 512, b = idx >> 2, a0 = (idx & 3) * 128;
#pragma unroll
        for (int i = 0; i < 4; ++i) dh[tid + i * 256] = dec_h[b * KDIM + tid + i * 256];
        __syncthreads();
        const int a = a0 + (tid & 127), kh = (tid >> 7) * 512;
        float s = 0.f;
#pragma unroll 8
        for (int k = 0; k < 512; ++k) s += dh[kh + k] * W_dec[(size_t)(kh + k) * ADIM + a];
        part[tid] = s;
        __syncthreads();
        if (tid < 128) {
            const int aa = a0 + tid;
            dterm[b * ADIM + aa] = part[tid] + part[tid + 128] + be[aa] + bd[aa] + ba[aa];
        }
    } else if (blk < 1152) {
        /* convA[(b*T+t)*32+c] = sum_j att_prev[b,t+j-50]*conv_w[c][j] */
        float* ap = smem;            /* 228  */
        float* w  = smem + 228;      /* 3232 */
        const int idx = blk - 640, b = idx >> 4, tt = idx & 15;
        const int t0 = tt * 128;
        for (int i = tid; i < 228; i += 256) {
            int t = t0 - 50 + i;
            ap[i] = (t >= 0 && t < T_LEN) ? att_prev[b * T_LEN + t] : 0.f;
        }
        for (int i = tid; i < CCH * KW; i += 256) w[i] = conv_w[i];
        __syncthreads();
        for (int idx2 = tid; idx2 < 128 * CCH; idx2 += 256) {
            int tl = idx2 >> 5, c = idx2 & 31;
            int t = t0 + tl;
            if (t < T_LEN) {
                float s = 0.f;
#pragma unroll
                for (int j = 0; j < KW; ++j) s += ap[tl + j] * w[c * KW + j];
                convA[(size_t)(b * T_LEN + t) * CCH + c] = (_Float16)s;
            }
        }
    } else {
        /* W_att [c=32][n=512] -> Wat f16 [n][c] */
#pragma unroll
        for (int rr = 0; rr < 2; ++rr) {
            const int n = tid * 2 + rr;
#pragma unroll
            for (int c = 0; c < CCH; ++c)
                Wat[n * CCH + c] = (_Float16)Wa[c * ADIM + n];
        }
    }
}

/* Fused GEMM+tanh+dot: epart[row] = sum_a tanh(enc@We + conv@Wa + dterm)[row,a]*g[a]
 * grid 1000 m-tiles, 256 threads = 4 waves, tile 64x512 (full N), wave 64x128.
 * B LDS is segment-swizzled: row nb seg s stored at slot s^((nb>>1)&3). */
__global__ __launch_bounds__(256) void k_gemm_e(const float* __restrict__ enc,
                                                const _Float16* __restrict__ Wet,
                                                const _Float16* __restrict__ convA,
                                                const _Float16* __restrict__ Wat,
                                                const float* __restrict__ dterm,
                                                const float* __restrict__ gvec,
                                                float* __restrict__ epart) {
    __shared__ __attribute__((aligned(16))) _Float16 Ah[64 * PADA];   /* 5 KB  */
    __shared__ __attribute__((aligned(16))) _Float16 Bh[512 * 32];    /* 32 KB */

    const int tid  = threadIdx.x;
    const int m0   = blockIdx.x * 64;
    const int wave = tid >> 6, lane = tid & 63;
    const int quad = lane >> 4, c16 = lane & 15;
    const int wn = wave * 128;

    float4_t acc[4][8];
#pragma unroll
    for (int i = 0; i < 4; ++i)
#pragma unroll
        for (int j = 0; j < 8; ++j) acc[i][j] = (float4_t){0.f, 0.f, 0.f, 0.f};

    /* A staging role: 4 threads per row, 8 f32 each */
    const int arow = tid >> 2, aseg = tid & 3;
    const float* aBase = enc + (size_t)(m0 + arow) * KDIM + aseg * 8;
    /* B glds role */
    const int rowl = lane >> 2, segst = lane & 3;

    /* prefetch A for kk=0 */
    float4_t pa0 = ((const float4_t*)aBase)[0];
    float4_t pa1 = ((const float4_t*)aBase)[1];

    for (int kk = 0; kk < 32; ++kk) {
        const int k0 = kk * 32;
        __syncthreads();
        *(half8_t*)&Ah[arow * PADA + aseg * 8] = pack8(pa0, pa1);
#pragma unroll
        for (int p = 0; p < 8; ++p) {
            const int nb = wn + p * 16 + rowl;
            const int segsrc = segst ^ ((nb >> 1) & 3);
            glds16(Wet + (size_t)nb * KDIM + k0 + segsrc * 8, &Bh[(wn + p * 16) * 32]);
        }
        __syncthreads();
        /* prefetch next A tile — overlaps MFMA phase */
        {
            const int kn = (kk < 31) ? (k0 + 32) : k0;
            pa0 = ((const float4_t*)(aBase + kn))[0];
            pa1 = ((const float4_t*)(aBase + kn))[1];
        }
        half8_t af[4], bf[8];
#pragma unroll
        for (int i = 0; i < 4; ++i)
            af[i] = *(const half8_t*)&Ah[(i * 16 + c16) * PADA + quad * 8];
#pragma unroll
        for (int j = 0; j < 8; ++j) {
            const int r = wn + j * 16 + c16;
            const int sb = quad ^ ((r >> 1) & 3);
            bf[j] = *(const half8_t*)&Bh[r * 32 + sb * 8];
        }
#pragma unroll
        for (int i = 0; i < 4; ++i)
#pragma unroll
            for (int j = 0; j < 8; ++j)
                acc[i][j] = __builtin_amdgcn_mfma_f32_16x16x32_f16(af[i], bf[j], acc[i][j], 0, 0, 0);
    }

    /* conv extension: one K=32 step; A2 = convA rows, B2 = Wat (store swizzled) */
    __syncthreads();
    *(half8_t*)&Ah[arow * PADA + aseg * 8] =
        *(const half8_t*)(convA + (size_t)(m0 + arow) * CCH + aseg * 8);
#pragma unroll
    for (int rr = 0; rr < 2; ++rr) {
        const int n = tid * 2 + rr;
        const int sw = (n >> 1) & 3;
#pragma unroll
        for (int s = 0; s < 4; ++s)
            *(half8_t*)&Bh[n * 32 + s * 8] = *(const half8_t*)(Wat + n * CCH + (s ^ sw) * 8);
    }
    __syncthreads();
    {
        half8_t af[4], bf[8];
#pragma unroll
        for (int i = 0; i < 4; ++i)
            af[i] = *(const half8_t*)&Ah[(i * 16 + c16) * PADA + quad * 8];
#pragma unroll
        for (int j = 0; j < 8; ++j) {
            const int r = wn + j * 16 + c16;
            const int sb = quad ^ ((r >> 1) & 3);
            bf[j] = *(const half8_t*)&Bh[r * 32 + sb * 8];
        }
#pragma unroll
        for (int i = 0; i < 4; ++i)
#pragma unroll
            for (int j = 0; j < 8; ++j)
                acc[i][j] = __builtin_amdgcn_mfma_f32_16x16x32_f16(af[i], bf[j], acc[i][j], 0, 0, 0);
    }

    /* epilogue: + dterm, tanh, *g, 16-lane reduce, combine 4 n-waves */
    float g[8], dt0[8], dt1[8];
    const int b0 = m0 / T_LEN, bt = (m0 + 63) / T_LEN;
    const int lim = (b0 + 1) * T_LEN;
#pragma unroll
    for (int j = 0; j < 8; ++j) {
        const int col = wn + j * 16 + c16;
        g[j]   = gvec[col];
        dt0[j] = dterm[b0 * ADIM + col];
        dt1[j] = dterm[bt * ADIM + col];
    }
    __syncthreads();
    float* e_lds = (float*)Ah;   /* [64][4] floats */
#pragma unroll
    for (int i = 0; i < 4; ++i) {
#pragma unroll
        for (int r = 0; r < 4; ++r) {
            const int rl = i * 16 + quad * 4 + r;
            const bool hi = (m0 + rl) >= lim;
            float s = 0.f;
#pragma unroll
            for (int j = 0; j < 8; ++j) {
                const float dv = hi ? dt1[j] : dt0[j];
                s += tanh_fast(acc[i][j][r] + dv) * g[j];
            }
#pragma unroll
            for (int off = 1; off < 16; off <<= 1) s += __shfl_xor(s, off);
            if (c16 == 0) e_lds[rl * 4 + wave] = s;
        }
    }
    __syncthreads();
    if (tid < 64) {
        float4_t q = ((const float4_t*)e_lds)[tid];
        epart[m0 + tid] = q.x + q.y + q.z + q.w;
    }
}

/* softmax over T with masking; logit = 2*epart, masked -> -2e15 */
__global__ __launch_bounds__(512) void k_softmax(const float* __restrict__ epart,
                                                 const int* __restrict__ enc_len,
                                                 float* __restrict__ attn) {
    __shared__ float ex[T_LEN];
    __shared__ float red[8];
    const int b = blockIdx.x, tid = threadIdx.x;
    const int len = enc_len[b];
    float lmax = -3.4e38f;
    for (int t = tid; t < T_LEN; t += 512) {
        float lg = (t < len) ? 2.f * epart[b * T_LEN + t] : -2e15f;
        ex[t] = lg;
        lmax = fmaxf(lmax, lg);
    }
    for (int off = 1; off < 64; off <<= 1) lmax = fmaxf(lmax, __shfl_xor(lmax, off));
    if ((tid & 63) == 0) red[tid >> 6] = lmax;
    __syncthreads();
    const float m = fmaxf(fmaxf(fmaxf(red[0], red[1]), fmaxf(red[2], red[3])),
                          fmaxf(fmaxf(red[4], red[5]), fmaxf(red[6], red[7])));
    float lsum = 0.f;
    for (int t = tid; t < T_LEN; t += 512) {
        float p = __expf(ex[t] - m);
        ex[t] = p;
        lsum += p;
    }
    for (int off = 1; off < 64; off <<= 1) lsum += __shfl_xor(lsum, off);
    __syncthreads();
    if ((tid & 63) == 0) red[tid >> 6] = lsum;
    __syncthreads();
    const float inv = 1.f / (red[0] + red[1] + red[2] + red[3] + red[4] + red[5] + red[6] + red[7]);
    for (int t = tid; t < T_LEN; t += 512) attn[b * T_LEN + t] = ex[t] * inv;
}

/* c partial: cpart[tc][b][d] = sum_{t in chunk} attn[b,t]*enc[b,t,d] */
__global__ __launch_bounds__(256) void k_cpart(const float* __restrict__ attn,
                                               const float* __restrict__ enc,
                                               float* __restrict__ cpart) {
    const int b = blockIdx.y, tc = blockIdx.x, tid = threadIdx.x;
    const int t0 = tc * 125;
    float4_t s = (float4_t){0.f, 0.f, 0.f, 0.f};
    const float4_t* ep = (const float4_t*)(enc + (size_t)b * T_LEN * KDIM) + tid;
    const float* ap = attn + b * T_LEN + t0;
#pragma unroll 5
    for (int tt = 0; tt < 125; ++tt) {
        const float w = ap[tt];
        float4_t v = ep[(size_t)(t0 + tt) * 256];
        s += v * w;
    }
    *(float4_t*)&cpart[(size_t)(tc * BATCH + b) * KDIM + tid * 4] = s;
}

/* out_c[b][o] = b_o[o] + sum_d (sum_p cpart[p][b][d]) * W_o[d][o] ; grid (32,4) x 256 */
__global__ __launch_bounds__(256) void k_out(const float* __restrict__ cpart,
                                             const float* __restrict__ W_o,
                                             const float* __restrict__ b_o,
                                             float* __restrict__ out_c) {
    __shared__ float cm[KDIM];
    const int b = blockIdx.x, tid = threadIdx.x;
    for (int d = tid; d < KDIM; d += 256) {
        float s = 0.f;
#pragma unroll
        for (int p = 0; p < 16; ++p) s += cpart[(size_t)(p * BATCH + b) * KDIM + d];
        cm[d] = s;
    }
    __syncthreads();
    const int o = blockIdx.y * 256 + tid;
    float s = b_o[o];
#pragma unroll 8
    for (int d = 0; d < KDIM; ++d) s += cm[d] * W_o[(size_t)d * KDIM + o];
    out_c[b * KDIM + o] = s;
}

extern "C" void kernel_launch(void* const* d_in, const int* in_sizes, int n_in,
                              void* d_out, int out_size, void* d_ws, size_t ws_size,
                              hipStream_t stream) {
    const float* enc      = (const float*)d_in[0];
    const int*   enc_len  = (const int*)d_in[1];
    const float* dec_h    = (const float*)d_in[2];
    const float* att_prev = (const float*)d_in[3];
    const float* W_enc    = (const float*)d_in[4];
    const float* b_enc    = (const float*)d_in[5];
    const float* W_dec    = (const float*)d_in[6];
    const float* b_dec    = (const float*)d_in[7];
    const float* W_att    = (const float*)d_in[8];
    const float* b_att    = (const float*)d_in[9];
    const float* conv_w   = (const float*)d_in[10];
    const float* gvec     = (const float*)d_in[11];
    const float* W_o      = (const float*)d_in[12];
    const float* b_o      = (const float*)d_in[13];

    float* out_c    = (float*)d_out;           /* 32*1024 */
    float* out_attn = out_c + BATCH * KDIM;    /* 32*2000 */

    char* ws = (char*)d_ws;
    _Float16* Wet   = (_Float16*)(ws + OFF_WENCT);
    _Float16* Wat   = (_Float16*)(ws + OFF_WATTT);
    _Float16* convA = (_Float16*)(ws + OFF_CONVA);
    float*    dterm = (float*)(ws + OFF_DTERM);
    float*    epart = (float*)(ws + OFF_EPART);
    float*    cpart = (float*)(ws + OFF_CPART);

    k_prep<<<1153, 256, 0, stream>>>(W_enc, W_att, dec_h, W_dec, b_enc, b_dec, b_att,
                                     att_prev, conv_w, Wet, Wat, dterm, convA);
    k_gemm_e<<<1000, 256, 0, stream>>>(enc, Wet, convA, Wat, dterm, gvec, epart);
    k_softmax<<<BATCH, 512, 0, stream>>>(epart, enc_len, out_attn);
    k_cpart<<<dim3(16, BATCH), 256, 0, stream>>>(out_attn, enc, cpart);
    k_out<<<dim3(BATCH, 4), 256, 0, stream>>>(cpart, W_o, b_o, out_c);
}

// Round 4
// 657.576 us; speedup vs baseline: 1.0070x; 1.0070x over previous
//
#include <hip/hip_runtime.h>
#include <stdint.h>
#include <stddef.h>

#define T_LEN   2000
#define BATCH   32
#define ROWS    64000      /* B*T */
#define KDIM    1024
#define ADIM    512
#define CCH     32
#define KW      101        /* 2*50+1 */

typedef _Float16 half8_t  __attribute__((ext_vector_type(8)));
typedef float    float4_t __attribute__((ext_vector_type(4)));

__device__ __forceinline__ half8_t pack8(float4_t a, float4_t b) {
    half8_t r;
    r[0] = (_Float16)a.x; r[1] = (_Float16)a.y;
    r[2] = (_Float16)a.z; r[3] = (_Float16)a.w;
    r[4] = (_Float16)b.x; r[5] = (_Float16)b.y;
    r[6] = (_Float16)b.z; r[7] = (_Float16)b.w;
    return r;
}

__device__ __forceinline__ float tanh_fast(float x) {
    float ax = __builtin_fabsf(x);
    ax = fminf(ax, 15.f);
    float e = __expf(2.f * ax);
    float t = 1.f - 2.f * __builtin_amdgcn_rcpf(e + 1.f);
    return (x < 0.f) ? -t : t;
}

/* async global->LDS, 16B/lane; LDS dest = wave-uniform base + lane*16 */
__device__ __forceinline__ void glds16(const void* g, void* l) {
    __builtin_amdgcn_global_load_lds((const __attribute__((address_space(1))) uint32_t*)g,
                                     (__attribute__((address_space(3))) uint32_t*)l,
                                     16, 0, 0);
}

/* ---- ws layout (bytes) ---- */
#define OFF_WENCT 0                  /* 512*1024 f16 = 1048576 */
#define OFF_WATTT 1048576            /* 512*32  f16 = 32768   */
#define OFF_CONVA 1081344            /* 64000*32 f32 = 8192000 */
#define OFF_DTERM 9273344            /* 32*512 f32 = 65536    */
#define OFF_EPART 9338880            /* 4*64000 f32 = 1024000 */
#define OFF_CPART 10362880           /* 16*32*1024 f32 = 2097152 -> end 12460032 */

/* ---- fused prep: [0,512) We transpose, [512,640) dterm, [640,1152) conv, [1152] Wat ---- */
__global__ __launch_bounds__(256) void k_prep(const float* __restrict__ We,
                                              const float* __restrict__ Wa,
                                              const float* __restrict__ dec_h,
                                              const float* __restrict__ W_dec,
                                              const float* __restrict__ be,
                                              const float* __restrict__ bd,
                                              const float* __restrict__ ba,
                                              const float* __restrict__ att_prev,
                                              const float* __restrict__ conv_w,
                                              _Float16* __restrict__ Wet,
                                              _Float16* __restrict__ Wat,
                                              float* __restrict__ dterm,
                                              float* __restrict__ convA) {
    __shared__ float smem[3460];
    const int blk = blockIdx.x, tid = threadIdx.x;

    if (blk < 512) {
        float (*tile)[33] = (float(*)[33])smem;
        const int k0 = (blk >> 4) * 32, n0 = (blk & 15) * 32;
        const int tx = tid & 31, ty = tid >> 5;
#pragma unroll
        for (int i = 0; i < 4; ++i)
            tile[ty + i * 8][tx] = We[(size_t)(k0 + ty + i * 8) * ADIM + n0 + tx];
        __syncthreads();
#pragma unroll
        for (int i = 0; i < 4; ++i)
            Wet[(size_t)(n0 + ty + i * 8) * KDIM + k0 + tx] = (_Float16)tile[tx][ty + i * 8];
    } else if (blk < 640) {
        float* dh = smem;
        float* part = smem + 1024;
        const int idx = blk - 512, b = idx >> 2, a0 = (idx & 3) * 128;
#pragma unroll
        for (int i = 0; i < 4; ++i) dh[tid + i * 256] = dec_h[b * KDIM + tid + i * 256];
        __syncthreads();
        const int a = a0 + (tid & 127), kh = (tid >> 7) * 512;
        float s = 0.f;
#pragma unroll 8
        for (int k = 0; k < 512; ++k) s += dh[kh + k] * W_dec[(size_t)(kh + k) * ADIM + a];
        part[tid] = s;
        __syncthreads();
        if (tid < 128) {
            const int aa = a0 + tid;
            dterm[b * ADIM + aa] = part[tid] + part[tid + 128] + be[aa] + bd[aa] + ba[aa];
        }
    } else if (blk < 1152) {
        float* ap = smem;
        float* w  = smem + 228;
        const int idx = blk - 640, b = idx >> 4, tt = idx & 15;
        const int t0 = tt * 128;
        for (int i = tid; i < 228; i += 256) {
            int t = t0 - 50 + i;
            ap[i] = (t >= 0 && t < T_LEN) ? att_prev[b * T_LEN + t] : 0.f;
        }
        for (int i = tid; i < CCH * KW; i += 256) w[i] = conv_w[i];
        __syncthreads();
        for (int idx2 = tid; idx2 < 128 * CCH; idx2 += 256) {
            int tl = idx2 >> 5, c = idx2 & 31;
            int t = t0 + tl;
            if (t < T_LEN) {
                float s = 0.f;
#pragma unroll
                for (int j = 0; j < KW; ++j) s += ap[tl + j] * w[c * KW + j];
                convA[(size_t)(b * T_LEN + t) * CCH + c] = s;
            }
        }
    } else {
#pragma unroll
        for (int rr = 0; rr < 2; ++rr) {
            const int n = tid * 2 + rr;
#pragma unroll
            for (int c = 0; c < CCH; ++c)
                Wat[n * CCH + c] = (_Float16)Wa[c * ADIM + n];
        }
    }
}

/* Fused GEMM+tanh+dot. grid (4 nc, 500 mt), 256 thr = 4 waves, tile 128x128,
 * wave 64x64, acc[4][4]. Double-buffered all-glds staging, one barrier/K-step.
 * LDS layouts are source-segment-swizzled for conflict-free frag reads:
 *   A (f32, 32/row): slot t of row r holds global seg (t - r)&7
 *   B (f16, 32/row): slot t of row r holds global seg (t - (r>>1))&3          */
__global__ __launch_bounds__(256, 3) void k_gemm_e(const float* __restrict__ enc,
                                                   const _Float16* __restrict__ Wet,
                                                   const float* __restrict__ convA,
                                                   const _Float16* __restrict__ Wat,
                                                   const float* __restrict__ dterm,
                                                   const float* __restrict__ gvec,
                                                   float* __restrict__ epart) {
    __shared__ __attribute__((aligned(16))) float    Af[2][128 * 32];  /* 32 KB */
    __shared__ __attribute__((aligned(16))) _Float16 Bh[2][128 * 32];  /* 16 KB */

    const int tid  = threadIdx.x;
    const int nc   = blockIdx.x, m0 = blockIdx.y * 128, n0 = nc * 128;
    const int wave = tid >> 6, lane = tid & 63;
    const int quad = lane >> 4, c16 = lane & 15;
    const int wm = (wave >> 1) * 64, wn = (wave & 1) * 64;

    /* staging lane roles + swizzle constants (row_local mod pattern folds out) */
    const int rlA = lane >> 3, segA = lane & 7;      /* A: 8 rows/issue, 8x4 f32   */
    const int rlB = lane >> 2, segB = lane & 3;      /* B: 16 rows/issue, 4x8 f16  */
    const int aOff = ((segA - rlA) & 7) * 4;                 /* f32 units */
    const int bOff = ((segB - ((rlB >> 1) & 3)) & 3) * 8;    /* f16 units */

    /* per-lane global bases */
    const float*    aG = enc + (size_t)(m0 + wave * 32 + rlA) * KDIM + aOff;
    const _Float16* bG = Wet + (size_t)(n0 + wave * 32 + rlB) * KDIM + bOff;
    const float*    aC = convA + (size_t)(m0 + wave * 32 + rlA) * CCH + aOff;
    const _Float16* bC = Wat + (size_t)(n0 + wave * 32 + rlB) * CCH + bOff;

    /* frag-read swizzled offsets (constant per lane) */
    const int aR0 = ((c16 + quad * 2 + 0) & 7) * 4;
    const int aR1 = ((c16 + quad * 2 + 1) & 7) * 4;
    const int bR  = ((quad + (c16 >> 1)) & 3) * 8;

    /* epilogue data, prefetched now */
    float g[4], dt0[4], dt1[4];
    const int b0 = m0 / T_LEN, b1 = (m0 + 127) / T_LEN;
    const int lim = (b0 + 1) * T_LEN;
#pragma unroll
    for (int j = 0; j < 4; ++j) {
        const int col = n0 + wn + j * 16 + c16;
        g[j]   = gvec[col];
        dt0[j] = dterm[b0 * ADIM + col];
        dt1[j] = dterm[b1 * ADIM + col];
    }

    float4_t acc[4][4];
#pragma unroll
    for (int i = 0; i < 4; ++i)
#pragma unroll
        for (int j = 0; j < 4; ++j) acc[i][j] = (float4_t){0.f, 0.f, 0.f, 0.f};

    /* prologue: stage chunk 0 into buf 0 */
#pragma unroll
    for (int i = 0; i < 4; ++i)
        glds16(aG + (size_t)i * 8 * KDIM, &Af[0][(wave * 32 + i * 8) * 32]);
#pragma unroll
    for (int i = 0; i < 2; ++i)
        glds16(bG + (size_t)i * 16 * KDIM, &Bh[0][(wave * 32 + i * 16) * 32]);
    __syncthreads();

    for (int kk = 0; kk < 33; ++kk) {
        const int cur = kk & 1, nxt = cur ^ 1;
        if (kk < 32) {
            if (kk + 1 < 32) {
                const int kn = (kk + 1) * 32;
#pragma unroll
                for (int i = 0; i < 4; ++i)
                    glds16(aG + (size_t)i * 8 * KDIM + kn, &Af[nxt][(wave * 32 + i * 8) * 32]);
#pragma unroll
                for (int i = 0; i < 2; ++i)
                    glds16(bG + (size_t)i * 16 * KDIM + kn, &Bh[nxt][(wave * 32 + i * 16) * 32]);
            } else {
#pragma unroll
                for (int i = 0; i < 4; ++i)
                    glds16(aC + (size_t)i * 8 * CCH, &Af[nxt][(wave * 32 + i * 8) * 32]);
#pragma unroll
                for (int i = 0; i < 2; ++i)
                    glds16(bC + (size_t)i * 16 * CCH, &Bh[nxt][(wave * 32 + i * 16) * 32]);
            }
        }
        half8_t af[4], bf[4];
#pragma unroll
        for (int i = 0; i < 4; ++i) {
            const float* base = &Af[cur][(wm + i * 16 + c16) * 32];
            float4_t u0 = *(const float4_t*)(base + aR0);
            float4_t u1 = *(const float4_t*)(base + aR1);
            af[i] = pack8(u0, u1);
        }
#pragma unroll
        for (int j = 0; j < 4; ++j)
            bf[j] = *(const half8_t*)&Bh[cur][(wn + j * 16 + c16) * 32 + bR];
#pragma unroll
        for (int i = 0; i < 4; ++i)
#pragma unroll
            for (int j = 0; j < 4; ++j)
                acc[i][j] = __builtin_amdgcn_mfma_f32_16x16x32_f16(af[i], bf[j], acc[i][j], 0, 0, 0);
        __syncthreads();
    }

    /* epilogue: + dterm, tanh, *g, 16-lane reduce, combine 2 n-waves */
    float* e_lds = (float*)&Bh[0][0];   /* [128][2] floats */
#pragma unroll
    for (int i = 0; i < 4; ++i) {
#pragma unroll
        for (int r = 0; r < 4; ++r) {
            const int rloc = wm + i * 16 + quad * 4 + r;
            const bool hi = (m0 + rloc) >= lim;
            float s = 0.f;
#pragma unroll
            for (int j = 0; j < 4; ++j)
                s += tanh_fast(acc[i][j][r] + (hi ? dt1[j] : dt0[j])) * g[j];
#pragma unroll
            for (int off = 1; off < 16; off <<= 1) s += __shfl_xor(s, off);
            if (c16 == 0) e_lds[rloc * 2 + (wave & 1)] = s;
        }
    }
    __syncthreads();
    if (tid < 128) {
        const float2 q = ((const float2*)e_lds)[tid];
        epart[nc * ROWS + m0 + tid] = q.x + q.y;
    }
}

/* softmax over T; logit = 2*sum_nc epart, masked -> -2e15 */
__global__ __launch_bounds__(512) void k_softmax(const float* __restrict__ epart,
                                                 const int* __restrict__ enc_len,
                                                 float* __restrict__ attn) {
    __shared__ float ex[T_LEN];
    __shared__ float red[8];
    const int b = blockIdx.x, tid = threadIdx.x;
    const int len = enc_len[b];
    float lmax = -3.4e38f;
    for (int t = tid; t < T_LEN; t += 512) {
        float e = epart[b * T_LEN + t] + epart[ROWS + b * T_LEN + t]
                + epart[2 * ROWS + b * T_LEN + t] + epart[3 * ROWS + b * T_LEN + t];
        float lg = (t < len) ? 2.f * e : -2e15f;
        ex[t] = lg;
        lmax = fmaxf(lmax, lg);
    }
    for (int off = 1; off < 64; off <<= 1) lmax = fmaxf(lmax, __shfl_xor(lmax, off));
    if ((tid & 63) == 0) red[tid >> 6] = lmax;
    __syncthreads();
    const float m = fmaxf(fmaxf(fmaxf(red[0], red[1]), fmaxf(red[2], red[3])),
                          fmaxf(fmaxf(red[4], red[5]), fmaxf(red[6], red[7])));
    float lsum = 0.f;
    for (int t = tid; t < T_LEN; t += 512) {
        float p = __expf(ex[t] - m);
        ex[t] = p;
        lsum += p;
    }
    for (int off = 1; off < 64; off <<= 1) lsum += __shfl_xor(lsum, off);
    __syncthreads();
    if ((tid & 63) == 0) red[tid >> 6] = lsum;
    __syncthreads();
    const float inv = 1.f / (red[0] + red[1] + red[2] + red[3] + red[4] + red[5] + red[6] + red[7]);
    for (int t = tid; t < T_LEN; t += 512) attn[b * T_LEN + t] = ex[t] * inv;
}

/* c partial: cpart[tc][b][d] = sum_{t in chunk} attn[b,t]*enc[b,t,d] */
__global__ __launch_bounds__(256) void k_cpart(const float* __restrict__ attn,
                                               const float* __restrict__ enc,
                                               float* __restrict__ cpart) {
    const int b = blockIdx.y, tc = blockIdx.x, tid = threadIdx.x;
    const int t0 = tc * 125;
    float4_t s = (float4_t){0.f, 0.f, 0.f, 0.f};
    const float4_t* ep = (const float4_t*)(enc + (size_t)b * T_LEN * KDIM) + tid;
    const float* ap = attn + b * T_LEN + t0;
#pragma unroll 5
    for (int tt = 0; tt < 125; ++tt) {
        const float w = ap[tt];
        float4_t v = ep[(size_t)(t0 + tt) * 256];
        s += v * w;
    }
    *(float4_t*)&cpart[(size_t)(tc * BATCH + b) * KDIM + tid * 4] = s;
}

/* out_c[b][o] = b_o[o] + sum_d (sum_p cpart[p][b][d]) * W_o[d][o] ; grid (32,4) x 256 */
__global__ __launch_bounds__(256) void k_out(const float* __restrict__ cpart,
                                             const float* __restrict__ W_o,
                                             const float* __restrict__ b_o,
                                             float* __restrict__ out_c) {
    __shared__ float cm[KDIM];
    const int b = blockIdx.x, tid = threadIdx.x;
    for (int d = tid; d < KDIM; d += 256) {
        float s = 0.f;
#pragma unroll
        for (int p = 0; p < 16; ++p) s += cpart[(size_t)(p * BATCH + b) * KDIM + d];
        cm[d] = s;
    }
    __syncthreads();
    const int o = blockIdx.y * 256 + tid;
    float s = b_o[o];
#pragma unroll 8
    for (int d = 0; d < KDIM; ++d) s += cm[d] * W_o[(size_t)d * KDIM + o];
    out_c[b * KDIM + o] = s;
}

extern "C" void kernel_launch(void* const* d_in, const int* in_sizes, int n_in,
                              void* d_out, int out_size, void* d_ws, size_t ws_size,
                              hipStream_t stream) {
    const float* enc      = (const float*)d_in[0];
    const int*   enc_len  = (const int*)d_in[1];
    const float* dec_h    = (const float*)d_in[2];
    const float* att_prev = (const float*)d_in[3];
    const float* W_enc    = (const float*)d_in[4];
    const float* b_enc    = (const float*)d_in[5];
    const float* W_dec    = (const float*)d_in[6];
    const float* b_dec    = (const float*)d_in[7];
    const float* W_att    = (const float*)d_in[8];
    const float* b_att    = (const float*)d_in[9];
    const float* conv_w   = (const float*)d_in[10];
    const float* gvec     = (const float*)d_in[11];
    const float* W_o      = (const float*)d_in[12];
    const float* b_o      = (const float*)d_in[13];

    float* out_c    = (float*)d_out;           /* 32*1024 */
    float* out_attn = out_c + BATCH * KDIM;    /* 32*2000 */

    char* ws = (char*)d_ws;
    _Float16* Wet    = (_Float16*)(ws + OFF_WENCT);
    _Float16* Wat    = (_Float16*)(ws + OFF_WATTT);
    float*    convAF = (float*)(ws + OFF_CONVA);
    float*    dterm  = (float*)(ws + OFF_DTERM);
    float*    epart  = (float*)(ws + OFF_EPART);
    float*    cpart  = (float*)(ws + OFF_CPART);

    k_prep<<<1153, 256, 0, stream>>>(W_enc, W_att, dec_h, W_dec, b_enc, b_dec, b_att,
                                     att_prev, conv_w, Wet, Wat, dterm, convAF);
    k_gemm_e<<<dim3(4, 500), 256, 0, stream>>>(enc, Wet, convAF, Wat, dterm, gvec, epart);
    k_softmax<<<BATCH, 512, 0, stream>>>(epart, enc_len, out_attn);
    k_cpart<<<dim3(16, BATCH), 256, 0, stream>>>(out_attn, enc, cpart);
    k_out<<<dim3(BATCH, 4), 256, 0, stream>>>(cpart, W_o, b_o, out_c);
}

// Round 5
// 611.059 us; speedup vs baseline: 1.0837x; 1.0761x over previous
//
#include <hip/hip_runtime.h>
#include <stdint.h>
#include <stddef.h>

#define T_LEN   2000
#define BATCH   32
#define ROWS    64000      /* B*T */
#define KDIM    1024
#define ADIM    512
#define CCH     32
#define KW      101        /* 2*50+1 */

typedef _Float16 half8_t  __attribute__((ext_vector_type(8)));
typedef _Float16 half4_t  __attribute__((ext_vector_type(4)));
typedef float    float4_t __attribute__((ext_vector_type(4)));

__device__ __forceinline__ half8_t pack8(float4_t a, float4_t b) {
    half8_t r;
    r[0] = (_Float16)a.x; r[1] = (_Float16)a.y;
    r[2] = (_Float16)a.z; r[3] = (_Float16)a.w;
    r[4] = (_Float16)b.x; r[5] = (_Float16)b.y;
    r[6] = (_Float16)b.z; r[7] = (_Float16)b.w;
    return r;
}

__device__ __forceinline__ float tanh_fast(float x) {
    float ax = __builtin_fabsf(x);
    ax = fminf(ax, 15.f);
    float e = __expf(2.f * ax);
    float t = 1.f - 2.f * __builtin_amdgcn_rcpf(e + 1.f);
    return (x < 0.f) ? -t : t;
}

/* async global->LDS, 16B/lane; LDS dest = wave-uniform base + lane*16 */
__device__ __forceinline__ void glds16(const void* g, void* l) {
    __builtin_amdgcn_global_load_lds((const __attribute__((address_space(1))) uint32_t*)g,
                                     (__attribute__((address_space(3))) uint32_t*)l,
                                     16, 0, 0);
}

/* ---- ws layouts (bytes) ----
 * main (f16):  WENCT 0 | WATTT 1048576 | CONVH 1081344 (4MB f16) | DTERM 5177344
 *              | EPART 5242880 (4x64000 f32) | CPART 6266880 | ENCH 8364032 (131MB)
 * fallback:    same head but CONVF 1081344 is 8MB f32 -> DTERM 9273344,
 *              EPART 9338880, CPART 10362880, end 12460032                     */
#define OFF_WENCT 0
#define OFF_WATTT 1048576
#define OFF_CONV  1081344
#define M_DTERM   5177344
#define M_EPART   5242880
#define M_CPART   6266880
#define M_ENCH    8364032
#define F_DTERM   9273344
#define F_EPART   9338880
#define F_CPART   10362880

/* ---- fused prep: [0,512) We transpose, [512,640) dterm, [640,1152) conv,
 *      [1152] Wat, [1153, 1153+32000) enc->f16 conversion (main path only) ---- */
__global__ __launch_bounds__(256) void k_prep(const float* __restrict__ We,
                                              const float* __restrict__ Wa,
                                              const float* __restrict__ dec_h,
                                              const float* __restrict__ W_dec,
                                              const float* __restrict__ be,
                                              const float* __restrict__ bd,
                                              const float* __restrict__ ba,
                                              const float* __restrict__ att_prev,
                                              const float* __restrict__ conv_w,
                                              const float* __restrict__ enc,
                                              _Float16* __restrict__ Wet,
                                              _Float16* __restrict__ Wat,
                                              float* __restrict__ dterm,
                                              void* __restrict__ convO,
                                              _Float16* __restrict__ encH,
                                              int f16mode) {
    __shared__ float smem[3460];
    const int blk = blockIdx.x, tid = threadIdx.x;

    if (blk >= 1153) {
        /* enc fp32 -> f16, 2048 elems/block */
        const size_t idx = (size_t)(blk - 1153) * 2048 + tid * 8;
        const float4_t* s = (const float4_t*)(enc + idx);
        float4_t v0 = s[0], v1 = s[1];
        *(half8_t*)(encH + idx) = pack8(v0, v1);
        return;
    }
    if (blk < 512) {
        float (*tile)[33] = (float(*)[33])smem;
        const int k0 = (blk >> 4) * 32, n0 = (blk & 15) * 32;
        const int tx = tid & 31, ty = tid >> 5;
#pragma unroll
        for (int i = 0; i < 4; ++i)
            tile[ty + i * 8][tx] = We[(size_t)(k0 + ty + i * 8) * ADIM + n0 + tx];
        __syncthreads();
#pragma unroll
        for (int i = 0; i < 4; ++i)
            Wet[(size_t)(n0 + ty + i * 8) * KDIM + k0 + tx] = (_Float16)tile[tx][ty + i * 8];
    } else if (blk < 640) {
        float* dh = smem;
        float* part = smem + 1024;
        const int idx = blk - 512, b = idx >> 2, a0 = (idx & 3) * 128;
#pragma unroll
        for (int i = 0; i < 4; ++i) dh[tid + i * 256] = dec_h[b * KDIM + tid + i * 256];
        __syncthreads();
        const int a = a0 + (tid & 127), kh = (tid >> 7) * 512;
        float s = 0.f;
#pragma unroll 8
        for (int k = 0; k < 512; ++k) s += dh[kh + k] * W_dec[(size_t)(kh + k) * ADIM + a];
        part[tid] = s;
        __syncthreads();
        if (tid < 128) {
            const int aa = a0 + tid;
            dterm[b * ADIM + aa] = part[tid] + part[tid + 128] + be[aa] + bd[aa] + ba[aa];
        }
    } else if (blk < 1152) {
        float* ap = smem;
        float* w  = smem + 228;
        const int idx = blk - 640, b = idx >> 4, tt = idx & 15;
        const int t0 = tt * 128;
        for (int i = tid; i < 228; i += 256) {
            int t = t0 - 50 + i;
            ap[i] = (t >= 0 && t < T_LEN) ? att_prev[b * T_LEN + t] : 0.f;
        }
        for (int i = tid; i < CCH * KW; i += 256) w[i] = conv_w[i];
        __syncthreads();
        for (int idx2 = tid; idx2 < 128 * CCH; idx2 += 256) {
            int tl = idx2 >> 5, c = idx2 & 31;
            int t = t0 + tl;
            if (t < T_LEN) {
                float s = 0.f;
#pragma unroll
                for (int j = 0; j < KW; ++j) s += ap[tl + j] * w[c * KW + j];
                const size_t o = (size_t)(b * T_LEN + t) * CCH + c;
                if (f16mode) ((_Float16*)convO)[o] = (_Float16)s;
                else         ((float*)convO)[o] = s;
            }
        }
    } else {
#pragma unroll
        for (int rr = 0; rr < 2; ++rr) {
            const int n = tid * 2 + rr;
#pragma unroll
            for (int c = 0; c < CCH; ++c)
                Wat[n * CCH + c] = (_Float16)Wa[c * ADIM + n];
        }
    }
}

/* Fused GEMM+tanh+dot. 2000 blocks (XCD-swizzled so the 4 nc-siblings of an
 * m-tile share one XCD's L2), 256 thr = 4 waves, tile 128x128, wave 64x64.
 * Double-buffered all-glds staging, seg-major lane mapping (2-way-max LDS
 * reads by construction), one barrier per K-step.
 * F16A: A staged from pre-converted encH (8KB/step); else fp32 enc (16KB). */
template<bool F16A>
__global__ __launch_bounds__(256, F16A ? 4 : 3)
void k_gemm_e(const void* __restrict__ encv,
              const _Float16* __restrict__ Wet,
              const void* __restrict__ convv,
              const _Float16* __restrict__ Wat,
              const float* __restrict__ dterm,
              const float* __restrict__ gvec,
              float* __restrict__ epart) {
    constexpr int ABYTES = F16A ? 8192 : 16384;
    __shared__ __attribute__((aligned(16))) char     Ab[2][ABYTES];
    __shared__ __attribute__((aligned(16))) _Float16 Bh[2][128 * 32];

    const int tid  = threadIdx.x;
    const int blk  = blockIdx.x;
    int nc, mt;
    if (blk < 1984) { nc = (blk >> 3) & 3; mt = (blk >> 5) * 8 + (blk & 7); }
    else            { int r = blk - 1984; nc = r >> 2; mt = 496 + (r & 3); }
    const int m0 = mt * 128, n0 = nc * 128;

    const int wave = tid >> 6, lane = tid & 63;
    const int quad = lane >> 4, c16 = lane & 15;
    const int wm = (wave >> 1) * 64, wn = (wave & 1) * 64;

    /* staging lane roles (seg-major): A f16/B: lane = seg*16+row; A f32: seg*8+row */
    const int rlB = lane & 15, sgB = lane >> 4;
    const int rlA = F16A ? (lane & 15) : (lane & 7);
    const int sgA = F16A ? (lane >> 4) : (lane >> 3);
    constexpr int AISS = F16A ? 2 : 4;              /* A glds issues per wave */
    constexpr int ARPC = F16A ? 16 : 8;             /* A rows per 1KB chunk   */
    constexpr int AEPS = F16A ? 8 : 4;              /* A elems per 16B seg    */

    const _Float16* encH = (const _Float16*)encv;
    const float*    encF = (const float*)encv;
    const _Float16* cvH  = (const _Float16*)convv;
    const float*    cvF  = (const float*)convv;

    /* per-lane global element offsets (row*stride + seg) */
    const size_t aRow = (size_t)(m0 + wave * 32 + rlA);
    const size_t bRow = (size_t)(n0 + wave * 32 + rlB);

    /* epilogue data */
    float g[4], dt0[4], dt1[4];
    const int b0 = m0 / T_LEN, b1 = (m0 + 127) / T_LEN;
    const int lim = (b0 + 1) * T_LEN;
#pragma unroll
    for (int j = 0; j < 4; ++j) {
        const int col = n0 + wn + j * 16 + c16;
        g[j]   = gvec[col];
        dt0[j] = dterm[b0 * ADIM + col];
        dt1[j] = dterm[b1 * ADIM + col];
    }

    float4_t acc[4][4];
#pragma unroll
    for (int i = 0; i < 4; ++i)
#pragma unroll
        for (int j = 0; j < 4; ++j) acc[i][j] = (float4_t){0.f, 0.f, 0.f, 0.f};

    /* ---- staging helpers (k0 = element column offset within row) ---- */
#define STAGE_A(buf, base, stride, k0)                                              \
    _Pragma("unroll")                                                               \
    for (int i = 0; i < AISS; ++i)                                                  \
        glds16((base) + ((aRow + i * ARPC) * (stride)) + (k0) + sgA * AEPS,         \
               &Ab[buf][(wave * AISS + i) * 1024]);
#define STAGE_B(buf, base, stride, k0)                                              \
    _Pragma("unroll")                                                               \
    for (int i = 0; i < 2; ++i)                                                     \
        glds16((base) + ((bRow + i * 16) * (stride)) + (k0) + sgB * 8,              \
               (char*)&Bh[buf][0] + (wave * 2 + i) * 1024);

    /* prologue: stage K-step 0 into buf 0 */
    if (F16A) { STAGE_A(0, encH, KDIM, 0) } else { STAGE_A(0, encF, KDIM, 0) }
    STAGE_B(0, Wet, KDIM, 0)
    __syncthreads();

    for (int kk = 0; kk < 33; ++kk) {
        const int cur = kk & 1, nxt = cur ^ 1;
        if (kk < 31) {
            const int kn = (kk + 1) * 32;
            if (F16A) { STAGE_A(nxt, encH, KDIM, kn) } else { STAGE_A(nxt, encF, KDIM, kn) }
            STAGE_B(nxt, Wet, KDIM, kn)
        } else if (kk == 31) {   /* stage the conv K-step */
            if (F16A) { STAGE_A(nxt, cvH, CCH, 0) } else { STAGE_A(nxt, cvF, CCH, 0) }
            STAGE_B(nxt, Wat, CCH, 0)
        }
        half8_t af[4], bf[4];
        if (F16A) {
            const _Float16* Ah = (const _Float16*)Ab[cur];
#pragma unroll
            for (int i = 0; i < 4; ++i) {
                const int row = wm + i * 16 + c16;
                af[i] = *(const half8_t*)(Ah + (row >> 4) * 512 + (quad * 16 + c16) * 8);
            }
        } else {
            const float* Afp = (const float*)Ab[cur];
#pragma unroll
            for (int i = 0; i < 4; ++i) {
                const int row = wm + i * 16 + c16;
                const float* cb = Afp + (row >> 3) * 256 + (row & 7) * 4;
                float4_t u0 = *(const float4_t*)(cb + (2 * quad) * 32);
                float4_t u1 = *(const float4_t*)(cb + (2 * quad + 1) * 32);
                af[i] = pack8(u0, u1);
            }
        }
#pragma unroll
        for (int j = 0; j < 4; ++j) {
            const int row = wn + j * 16 + c16;
            bf[j] = *(const half8_t*)(&Bh[cur][0] + (row >> 4) * 512 + (quad * 16 + c16) * 8);
        }
#pragma unroll
        for (int i = 0; i < 4; ++i)
#pragma unroll
            for (int j = 0; j < 4; ++j)
                acc[i][j] = __builtin_amdgcn_mfma_f32_16x16x32_f16(af[i], bf[j], acc[i][j], 0, 0, 0);
        __syncthreads();
    }

    /* epilogue: + dterm, tanh, *g, 16-lane reduce, combine 2 n-waves */
    float* e_lds = (float*)&Bh[0][0];   /* [128][2] floats */
#pragma unroll
    for (int i = 0; i < 4; ++i) {
#pragma unroll
        for (int r = 0; r < 4; ++r) {
            const int rloc = wm + i * 16 + quad * 4 + r;
            const bool hi = (m0 + rloc) >= lim;
            float s = 0.f;
#pragma unroll
            for (int j = 0; j < 4; ++j)
                s += tanh_fast(acc[i][j][r] + (hi ? dt1[j] : dt0[j])) * g[j];
#pragma unroll
            for (int off = 1; off < 16; off <<= 1) s += __shfl_xor(s, off);
            if (c16 == 0) e_lds[rloc * 2 + (wave & 1)] = s;
        }
    }
    __syncthreads();
    if (tid < 128) {
        const float2 q = ((const float2*)e_lds)[tid];
        epart[nc * ROWS + m0 + tid] = q.x + q.y;
    }
#undef STAGE_A
#undef STAGE_B
}

/* softmax over T; logit = 2*sum_nc epart, masked -> -2e15 */
__global__ __launch_bounds__(512) void k_softmax(const float* __restrict__ epart,
                                                 const int* __restrict__ enc_len,
                                                 float* __restrict__ attn) {
    __shared__ float ex[T_LEN];
    __shared__ float red[8];
    const int b = blockIdx.x, tid = threadIdx.x;
    const int len = enc_len[b];
    float lmax = -3.4e38f;
    for (int t = tid; t < T_LEN; t += 512) {
        float e = epart[b * T_LEN + t] + epart[ROWS + b * T_LEN + t]
                + epart[2 * ROWS + b * T_LEN + t] + epart[3 * ROWS + b * T_LEN + t];
        float lg = (t < len) ? 2.f * e : -2e15f;
        ex[t] = lg;
        lmax = fmaxf(lmax, lg);
    }
    for (int off = 1; off < 64; off <<= 1) lmax = fmaxf(lmax, __shfl_xor(lmax, off));
    if ((tid & 63) == 0) red[tid >> 6] = lmax;
    __syncthreads();
    const float m = fmaxf(fmaxf(fmaxf(red[0], red[1]), fmaxf(red[2], red[3])),
                          fmaxf(fmaxf(red[4], red[5]), fmaxf(red[6], red[7])));
    float lsum = 0.f;
    for (int t = tid; t < T_LEN; t += 512) {
        float p = __expf(ex[t] - m);
        ex[t] = p;
        lsum += p;
    }
    for (int off = 1; off < 64; off <<= 1) lsum += __shfl_xor(lsum, off);
    __syncthreads();
    if ((tid & 63) == 0) red[tid >> 6] = lsum;
    __syncthreads();
    const float inv = 1.f / (red[0] + red[1] + red[2] + red[3] + red[4] + red[5] + red[6] + red[7]);
    for (int t = tid; t < T_LEN; t += 512) attn[b * T_LEN + t] = ex[t] * inv;
}

/* c partial from f16 enc copy */
__global__ __launch_bounds__(256) void k_cpart_h(const float* __restrict__ attn,
                                                 const _Float16* __restrict__ encH,
                                                 float* __restrict__ cpart) {
    const int b = blockIdx.y, tc = blockIdx.x, tid = threadIdx.x;
    const int t0 = tc * 125;
    float4_t s = (float4_t){0.f, 0.f, 0.f, 0.f};
    const half4_t* ep = (const half4_t*)(encH + (size_t)b * T_LEN * KDIM) + tid;
    const float* ap = attn + b * T_LEN + t0;
#pragma unroll 5
    for (int tt = 0; tt < 125; ++tt) {
        const float w = ap[tt];
        half4_t v = ep[(size_t)(t0 + tt) * 256];
        s.x += w * (float)v[0]; s.y += w * (float)v[1];
        s.z += w * (float)v[2]; s.w += w * (float)v[3];
    }
    *(float4_t*)&cpart[(size_t)(tc * BATCH + b) * KDIM + tid * 4] = s;
}

/* c partial from fp32 enc (fallback) */
__global__ __launch_bounds__(256) void k_cpart_f(const float* __restrict__ attn,
                                                 const float* __restrict__ enc,
                                                 float* __restrict__ cpart) {
    const int b = blockIdx.y, tc = blockIdx.x, tid = threadIdx.x;
    const int t0 = tc * 125;
    float4_t s = (float4_t){0.f, 0.f, 0.f, 0.f};
    const float4_t* ep = (const float4_t*)(enc + (size_t)b * T_LEN * KDIM) + tid;
    const float* ap = attn + b * T_LEN + t0;
#pragma unroll 5
    for (int tt = 0; tt < 125; ++tt) {
        const float w = ap[tt];
        float4_t v = ep[(size_t)(t0 + tt) * 256];
        s += v * w;
    }
    *(float4_t*)&cpart[(size_t)(tc * BATCH + b) * KDIM + tid * 4] = s;
}

/* out_c[b][o] = b_o[o] + sum_d (sum_p cpart[p][b][d]) * W_o[d][o] ; grid (32,4) x 256 */
__global__ __launch_bounds__(256) void k_out(const float* __restrict__ cpart,
                                             const float* __restrict__ W_o,
                                             const float* __restrict__ b_o,
                                             float* __restrict__ out_c) {
    __shared__ float cm[KDIM];
    const int b = blockIdx.x, tid = threadIdx.x;
    for (int d = tid; d < KDIM; d += 256) {
        float s = 0.f;
#pragma unroll
        for (int p = 0; p < 16; ++p) s += cpart[(size_t)(p * BATCH + b) * KDIM + d];
        cm[d] = s;
    }
    __syncthreads();
    const int o = blockIdx.y * 256 + tid;
    float s = b_o[o];
#pragma unroll 8
    for (int d = 0; d < KDIM; ++d) s += cm[d] * W_o[(size_t)d * KDIM + o];
    out_c[b * KDIM + o] = s;
}

extern "C" void kernel_launch(void* const* d_in, const int* in_sizes, int n_in,
                              void* d_out, int out_size, void* d_ws, size_t ws_size,
                              hipStream_t stream) {
    const float* enc      = (const float*)d_in[0];
    const int*   enc_len  = (const int*)d_in[1];
    const float* dec_h    = (const float*)d_in[2];
    const float* att_prev = (const float*)d_in[3];
    const float* W_enc    = (const float*)d_in[4];
    const float* b_enc    = (const float*)d_in[5];
    const float* W_dec    = (const float*)d_in[6];
    const float* b_dec    = (const float*)d_in[7];
    const float* W_att    = (const float*)d_in[8];
    const float* b_att    = (const float*)d_in[9];
    const float* conv_w   = (const float*)d_in[10];
    const float* gvec     = (const float*)d_in[11];
    const float* W_o      = (const float*)d_in[12];
    const float* b_o      = (const float*)d_in[13];

    float* out_c    = (float*)d_out;           /* 32*1024 */
    float* out_attn = out_c + BATCH * KDIM;    /* 32*2000 */

    char* ws = (char*)d_ws;
    _Float16* Wet = (_Float16*)(ws + OFF_WENCT);
    _Float16* Wat = (_Float16*)(ws + OFF_WATTT);

    const size_t needMain = (size_t)M_ENCH + (size_t)ROWS * KDIM * 2;
    const bool f16p = ws_size >= needMain;

    if (f16p) {
        _Float16* convH = (_Float16*)(ws + OFF_CONV);
        float*    dterm = (float*)(ws + M_DTERM);
        float*    epart = (float*)(ws + M_EPART);
        float*    cpart = (float*)(ws + M_CPART);
        _Float16* encH  = (_Float16*)(ws + M_ENCH);

        k_prep<<<1153 + 32000, 256, 0, stream>>>(W_enc, W_att, dec_h, W_dec, b_enc, b_dec,
                                                 b_att, att_prev, conv_w, enc,
                                                 Wet, Wat, dterm, convH, encH, 1);
        k_gemm_e<true><<<2000, 256, 0, stream>>>(encH, Wet, convH, Wat, dterm, gvec, epart);
        k_softmax<<<BATCH, 512, 0, stream>>>(epart, enc_len, out_attn);
        k_cpart_h<<<dim3(16, BATCH), 256, 0, stream>>>(out_attn, encH, cpart);
        k_out<<<dim3(BATCH, 4), 256, 0, stream>>>(cpart, W_o, b_o, out_c);
    } else {
        float* convF = (float*)(ws + OFF_CONV);
        float* dterm = (float*)(ws + F_DTERM);
        float* epart = (float*)(ws + F_EPART);
        float* cpart = (float*)(ws + F_CPART);

        k_prep<<<1153, 256, 0, stream>>>(W_enc, W_att, dec_h, W_dec, b_enc, b_dec,
                                         b_att, att_prev, conv_w, enc,
                                         Wet, Wat, dterm, convF, (_Float16*)nullptr, 0);
        k_gemm_e<false><<<2000, 256, 0, stream>>>(enc, Wet, convF, Wat, dterm, gvec, epart);
        k_softmax<<<BATCH, 512, 0, stream>>>(epart, enc_len, out_attn);
        k_cpart_f<<<dim3(16, BATCH), 256, 0, stream>>>(out_attn, enc, cpart);
        k_out<<<dim3(BATCH, 4), 256, 0, stream>>>(cpart, W_o, b_o, out_c);
    }
}